// Round 10
// baseline (499.604 us; speedup 1.0000x reference)
//
#include <hip/hip_runtime.h>
#include <math.h>

#define T_IN 2048
#define TP   2051      // T+3 conv output length
#define F    256
#define H    384
#define BK   16
#define NT2  129       // 16-t tiles in k2
#define TT2  2064      // 129*16: padded t-extent of [b][t] arrays

__device__ __forceinline__ float logsig(float z) {
    return (z >= 0.0f) ? -log1pf(__expf(-z)) : z - log1pf(__expf(z));
}

// ========== PREP: conv -> xp[t][f] | q,o at t=2050 | zero zf/ticket ==========
__global__ __launch_bounds__(256) void prep(
    const float* __restrict__ x, const float* __restrict__ cw, const float* __restrict__ cb,
    const float* __restrict__ Wq, const float* __restrict__ bq,
    const float* __restrict__ Wo, const float* __restrict__ bo,
    float* __restrict__ xp, float* __restrict__ qv, float* __restrict__ ov,
    float* __restrict__ zf, int* __restrict__ ticket) {
    int bx = blockIdx.x, tid = threadIdx.x;
    if (bx < 513) {                       // ---- conv: 4 t-rows/block
        int t = bx * 4 + (tid >> 6);
        int f4 = tid & 63;
        if (t >= TP) return;
        float w4[4] = {cw[0], cw[1], cw[2], cw[3]};
        float bb = cb[0];
        float4 acc = {bb, bb, bb, bb};
        #pragma unroll
        for (int j = 0; j < 4; ++j) {
            int tt = t - 3 + j;
            if (tt >= 0 && tt < T_IN) {
                float4 xv = *(const float4*)&x[tt * 256 + f4 * 4];
                float wj = w4[j];
                acc.x = fmaf(wj, xv.x, acc.x);
                acc.y = fmaf(wj, xv.y, acc.y);
                acc.z = fmaf(wj, xv.z, acc.z);
                acc.w = fmaf(wj, xv.w, acc.w);
            }
        }
        ((float4*)xp)[t * 64 + f4] = acc;
    } else if (bx < 519) {                // ---- q/o at t=2050: xp row = cb + cw0*x[2047]
        int lane = tid & 63, wid = tid >> 6;
        float w0 = cw[0], bb = cb[0];
        float4 xr = *(const float4*)&x[2047 * 256 + lane * 4];
        float4 xv = {bb + w0 * xr.x, bb + w0 * xr.y, bb + w0 * xr.z, bb + w0 * xr.w};
        for (int r = 0; r < 16; ++r) {
            int row = (bx - 513) * 64 + wid * 16 + r;
            float4 q4 = *(const float4*)&Wq[row * 256 + lane * 4];
            float4 o4 = *(const float4*)&Wo[row * 256 + lane * 4];
            float aq = fmaf(xv.x, q4.x, fmaf(xv.y, q4.y, fmaf(xv.z, q4.z, xv.w * q4.w)));
            float ao = fmaf(xv.x, o4.x, fmaf(xv.y, o4.y, fmaf(xv.z, o4.z, xv.w * o4.w)));
            #pragma unroll
            for (int off = 32; off; off >>= 1) {
                aq += __shfl_down(aq, off, 64);
                ao += __shfl_down(ao, off, 64);
            }
            if (lane == 0) {
                qv[row] = aq + bq[row];
                ov[row] = 1.0f / (1.0f + __expf(-(ao + bo[row])));
            }
        }
    } else {                              // ---- zero z-accumulator, G, ticket
        if (tid < 256) zf[tid] = 0.0f;
        if (tid == 0) { zf[256] = 0.0f; ticket[0] = 0; }
    }
}

// ========== K2: R4-proven SGEMM tile 16t x 64b x 3 mats, grid (129,6) ==========
// 256 thr: tx=tid&31 (2 b's), ty=tid>>5 (2 t's), 12 acc/thread.
// Epilogue: bias+activation, LDS transpose -> zkT/aiT/lfT in [b][t] layout.
__global__ __launch_bounds__(256) void k2_proj(
    const float* __restrict__ xp,
    const float* __restrict__ Wk, const float* __restrict__ bk,
    const float* __restrict__ Wi, const float* __restrict__ bi,
    const float* __restrict__ Wf, const float* __restrict__ bf,
    float* __restrict__ zkT, float* __restrict__ aiT, float* __restrict__ lfT) {
    __shared__ float alds[BK][20];      // xp^T [k][t]
    __shared__ float wlds[3][BK][68];   // W^T  [j][k][b]
    __shared__ float tb[64][17];        // transpose staging [b][t]
    int tid = threadIdx.x;
    int t0 = blockIdx.x * 16, b0 = blockIdx.y * 64;
    int tx = tid & 31, ty = tid >> 5;
    const float* Wg[3] = {Wk, Wi, Wf};

    float acc[3][4];
    #pragma unroll
    for (int j = 0; j < 3; ++j)
        #pragma unroll
        for (int u = 0; u < 4; ++u) acc[j][u] = 0.0f;

    int xr = tid >> 4, xk = tid & 15;
    int wr = tid >> 2, wsl = tid & 3;

    for (int k0 = 0; k0 < 256; k0 += BK) {
        __syncthreads();
        float xv = 0.0f;
        int tg = t0 + xr;
        if (tg < TP) xv = xp[tg * 256 + k0 + xk];
        alds[xk][xr] = xv;
        #pragma unroll
        for (int j = 0; j < 3; ++j) {
            float4 wv = *(const float4*)&Wg[j][(b0 + wr) * 256 + k0 + wsl * 4];
            wlds[j][wsl * 4 + 0][wr] = wv.x;
            wlds[j][wsl * 4 + 1][wr] = wv.y;
            wlds[j][wsl * 4 + 2][wr] = wv.z;
            wlds[j][wsl * 4 + 3][wr] = wv.w;
        }
        __syncthreads();
        #pragma unroll
        for (int kk = 0; kk < BK; ++kk) {
            float2 a2 = *(const float2*)&alds[kk][ty * 2];
            #pragma unroll
            for (int j = 0; j < 3; ++j) {
                float2 b2 = *(const float2*)&wlds[j][kk][2 * tx];
                acc[j][0] = fmaf(a2.x, b2.x, acc[j][0]);
                acc[j][1] = fmaf(a2.x, b2.y, acc[j][1]);
                acc[j][2] = fmaf(a2.y, b2.x, acc[j][2]);
                acc[j][3] = fmaf(a2.y, b2.y, acc[j][3]);
            }
        }
    }
    // ---- epilogue: 3x (bias/act -> LDS transpose -> [b][t] float4 store)
    int bA = b0 + 2 * tx;
    const float sc = 0.05103103630798287f;  // 1/sqrt(384)
    float2 bk2 = *(const float2*)&bk[bA];
    float2 bi2 = *(const float2*)&bi[bA];
    float2 bf2 = *(const float2*)&bf[bA];
    int r = tid >> 2, c4 = (tid & 3) * 4;
    long orow = (long)(b0 + r) * TT2 + t0 + c4;

    __syncthreads();
    tb[2 * tx + 0][2 * ty + 0] = (acc[0][0] + bk2.x) * sc;
    tb[2 * tx + 1][2 * ty + 0] = (acc[0][1] + bk2.y) * sc;
    tb[2 * tx + 0][2 * ty + 1] = (acc[0][2] + bk2.x) * sc;
    tb[2 * tx + 1][2 * ty + 1] = (acc[0][3] + bk2.y) * sc;
    __syncthreads();
    {
        float4 o = {tb[r][c4], tb[r][c4 + 1], tb[r][c4 + 2], tb[r][c4 + 3]};
        *(float4*)&zkT[orow] = o;
    }
    __syncthreads();
    tb[2 * tx + 0][2 * ty + 0] = acc[1][0] + bi2.x;
    tb[2 * tx + 1][2 * ty + 0] = acc[1][1] + bi2.y;
    tb[2 * tx + 0][2 * ty + 1] = acc[1][2] + bi2.x;
    tb[2 * tx + 1][2 * ty + 1] = acc[1][3] + bi2.y;
    __syncthreads();
    {
        float4 o = {tb[r][c4], tb[r][c4 + 1], tb[r][c4 + 2], tb[r][c4 + 3]};
        *(float4*)&aiT[orow] = o;
    }
    __syncthreads();
    tb[2 * tx + 0][2 * ty + 0] = logsig(acc[2][0] + bf2.x);
    tb[2 * tx + 1][2 * ty + 0] = logsig(acc[2][1] + bf2.y);
    tb[2 * tx + 0][2 * ty + 1] = logsig(acc[2][2] + bf2.x);
    tb[2 * tx + 1][2 * ty + 1] = logsig(acc[2][3] + bf2.y);
    __syncthreads();
    {
        float4 o = {tb[r][c4], tb[r][c4 + 1], tb[r][c4 + 2], tb[r][c4 + 3]};
        *(float4*)&lfT[orow] = o;
    }
}

// ========== T: per-b full-sequence scan. grid 384 x 64 (one wave per b) ==========
// L is a register accumulator (no scan arrays). ai/lf/zk reads are wave-uniform
// [b][t] rows; xp float4 reads independent/prefetchable. Atomic z/G + ticket GEMV.
__global__ __launch_bounds__(64) void t_scan(
    const float* __restrict__ xp, const float* __restrict__ zkT,
    const float* __restrict__ aiT, const float* __restrict__ lfT,
    const float* __restrict__ qv, const float* __restrict__ ov,
    const float* __restrict__ Wv, const float* __restrict__ bv,
    float* __restrict__ zf, int* __restrict__ ticket, float* __restrict__ out) {
    int b = blockIdx.x;
    int lane = threadIdx.x;
    const float* zr = zkT + (long)b * TT2;
    const float* ar = aiT + (long)b * TT2;
    const float* lr = lfT + (long)b * TT2;
    float qb = qv[b];
    float4 z4 = {0.f, 0.f, 0.f, 0.f};
    float Gb = 0.f, L = 0.f;
    // peel t = 2050..2048 (2051 = 3 + 256*8)
    #pragma unroll
    for (int t = 2050; t >= 2048; --t) {
        float e = __expf(ar[t] + L) * zr[t] * qb;
        L += lr[t];
        float4 xv = *(const float4*)&xp[t * 256 + lane * 4];
        z4.x = fmaf(e, xv.x, z4.x);
        z4.y = fmaf(e, xv.y, z4.y);
        z4.z = fmaf(e, xv.z, z4.z);
        z4.w = fmaf(e, xv.w, z4.w);
        Gb += e;
    }
    for (int c = 0; c < 256; ++c) {
        int s = 2040 - 8 * c;
        float a8[8], l8[8], k8[8];
        float4 x8[8];
        #pragma unroll
        for (int u = 0; u < 8; ++u) {
            a8[u] = ar[s + u];
            l8[u] = lr[s + u];
            k8[u] = zr[s + u];
            x8[u] = *(const float4*)&xp[(s + u) * 256 + lane * 4];
        }
        #pragma unroll
        for (int u = 7; u >= 0; --u) {
            float e = __expf(a8[u] + L) * k8[u] * qb;
            L += l8[u];
            z4.x = fmaf(e, x8[u].x, z4.x);
            z4.y = fmaf(e, x8[u].y, z4.y);
            z4.z = fmaf(e, x8[u].z, z4.z);
            z4.w = fmaf(e, x8[u].w, z4.w);
            Gb += e;
        }
    }
    atomicAdd(&zf[lane * 4 + 0], z4.x);
    atomicAdd(&zf[lane * 4 + 1], z4.y);
    atomicAdd(&zf[lane * 4 + 2], z4.z);
    atomicAdd(&zf[lane * 4 + 3], z4.w);
    if (lane == 0) atomicAdd(&zf[256], Gb);
    __threadfence();
    int lastv = 0;
    if (lane == 0) lastv = (atomicAdd(ticket, 1) == 383) ? 1 : 0;
    lastv = __shfl(lastv, 0, 64);
    if (!lastv) return;
    // ---- last wave: final GEMV h = ov * (Wv z + bv G) / max(|G|,1)
    __threadfence();
    float4 zv;
    zv.x = __hip_atomic_load(&zf[lane * 4 + 0], __ATOMIC_RELAXED, __HIP_MEMORY_SCOPE_AGENT);
    zv.y = __hip_atomic_load(&zf[lane * 4 + 1], __ATOMIC_RELAXED, __HIP_MEMORY_SCOPE_AGENT);
    zv.z = __hip_atomic_load(&zf[lane * 4 + 2], __ATOMIC_RELAXED, __HIP_MEMORY_SCOPE_AGENT);
    zv.w = __hip_atomic_load(&zf[lane * 4 + 3], __ATOMIC_RELAXED, __HIP_MEMORY_SCOPE_AGENT);
    float G = __hip_atomic_load(&zf[256], __ATOMIC_RELAXED, __HIP_MEMORY_SCOPE_AGENT);
    float den = fmaxf(fabsf(G), 1.0f);
    for (int row = 0; row < 384; ++row) {
        float4 wv4 = *(const float4*)&Wv[row * 256 + lane * 4];
        float a = fmaf(zv.x, wv4.x, fmaf(zv.y, wv4.y, fmaf(zv.z, wv4.z, zv.w * wv4.w)));
        #pragma unroll
        for (int off = 32; off; off >>= 1) a += __shfl_down(a, off, 64);
        if (lane == 0) out[row] = ov[row] * (a + bv[row] * G) / den;
    }
}

extern "C" void kernel_launch(void* const* d_in, const int* in_sizes, int n_in,
                              void* d_out, int out_size, void* d_ws, size_t ws_size,
                              hipStream_t stream) {
    const float* x  = (const float*)d_in[0];
    const float* Wq = (const float*)d_in[1];  const float* bq = (const float*)d_in[2];
    const float* Wk = (const float*)d_in[3];  const float* bk = (const float*)d_in[4];
    const float* Wv = (const float*)d_in[5];  const float* bv = (const float*)d_in[6];
    const float* Wi = (const float*)d_in[7];  const float* bi = (const float*)d_in[8];
    const float* Wf = (const float*)d_in[9];  const float* bf = (const float*)d_in[10];
    const float* Wo = (const float*)d_in[11]; const float* bo = (const float*)d_in[12];
    const float* cw = (const float*)d_in[13]; const float* cb = (const float*)d_in[14];
    float* out = (float*)d_out;

    float* ws = (float*)d_ws;
    float* xp  = ws;                       // TP*F = 525056
    float* zkT = xp  + TP * F;             // 384*2064 = 792576
    float* aiT = zkT + H * TT2;
    float* lfT = aiT + H * TT2;
    float* qv  = lfT + H * TT2;            // H
    float* ov  = qv  + H;                  // H
    float* zf  = ov  + H;                  // 257: z[256] + G
    int*   tk  = (int*)(zf + 260);         // ticket

    prep<<<520, 256, 0, stream>>>(x, cw, cb, Wq, bq, Wo, bo, xp, qv, ov, zf, tk);
    k2_proj<<<dim3(NT2, 6), 256, 0, stream>>>(xp, Wk, bk, Wi, bi, Wf, bf, zkT, aiT, lfT);
    t_scan<<<384, 64, 0, stream>>>(xp, zkT, aiT, lfT, qv, ov, Wv, bv, zf, tk, out);
}

// Round 11
// 183.548 us; speedup vs baseline: 2.7219x; 2.7219x over previous
//
#include <hip/hip_runtime.h>
#include <math.h>

#define T_IN 2048
#define TP   2051      // T+3 conv output length
#define F    256
#define H    384
#define TT   2080      // xpT stride (65*32)
#define WTS  98304     // 256*384
#define NCS  260       // cs rows (65 blocks * 4 chunks of 8t)
#define NC3  257       // chunks with t < TP

__device__ __forceinline__ float logsig(float z) {
    return (z >= 0.0f) ? -log1pf(__expf(-z)) : z - log1pf(__expf(z));
}

// ========== PREP: conv -> xp[t][f] + xpT[k][t] | Wt[j][k][b] | q,o ==========
__global__ __launch_bounds__(256) void prep(
    const float* __restrict__ x, const float* __restrict__ cw, const float* __restrict__ cb,
    const float* __restrict__ Wk, const float* __restrict__ Wi, const float* __restrict__ Wf,
    const float* __restrict__ Wq, const float* __restrict__ bq,
    const float* __restrict__ Wo, const float* __restrict__ bo,
    float* __restrict__ xp, float* __restrict__ xpT, float* __restrict__ Wt,
    float* __restrict__ qv, float* __restrict__ ov) {
    int bx = blockIdx.x, tid = threadIdx.x;
    if (bx < 513) {                       // ---- conv: 4 t-rows/block, dual-layout store
        int t = bx * 4 + (tid >> 6);
        int f4 = tid & 63;
        if (t >= TP) return;
        float w4[4] = {cw[0], cw[1], cw[2], cw[3]};
        float bb = cb[0];
        float4 acc = {bb, bb, bb, bb};
        #pragma unroll
        for (int j = 0; j < 4; ++j) {
            int tt = t - 3 + j;
            if (tt >= 0 && tt < T_IN) {
                float4 xv = *(const float4*)&x[tt * 256 + f4 * 4];
                float wj = w4[j];
                acc.x = fmaf(wj, xv.x, acc.x);
                acc.y = fmaf(wj, xv.y, acc.y);
                acc.z = fmaf(wj, xv.z, acc.z);
                acc.w = fmaf(wj, xv.w, acc.w);
            }
        }
        ((float4*)xp)[t * 64 + f4] = acc;
        int k0 = f4 * 4;
        xpT[(k0 + 0) * TT + t] = acc.x;
        xpT[(k0 + 1) * TT + t] = acc.y;
        xpT[(k0 + 2) * TT + t] = acc.z;
        xpT[(k0 + 3) * TT + t] = acc.w;
    } else if (bx < 519) {                // ---- q/o at t=2050 (xp row = cb + cw0*x[2047])
        int lane = tid & 63, wid = tid >> 6;
        float w0 = cw[0], bb = cb[0];
        float4 xr = *(const float4*)&x[2047 * 256 + lane * 4];
        float4 xv = {bb + w0 * xr.x, bb + w0 * xr.y, bb + w0 * xr.z, bb + w0 * xr.w};
        for (int r = 0; r < 16; ++r) {
            int row = (bx - 513) * 64 + wid * 16 + r;
            float4 q4 = *(const float4*)&Wq[row * 256 + lane * 4];
            float4 o4 = *(const float4*)&Wo[row * 256 + lane * 4];
            float aq = fmaf(xv.x, q4.x, fmaf(xv.y, q4.y, fmaf(xv.z, q4.z, xv.w * q4.w)));
            float ao = fmaf(xv.x, o4.x, fmaf(xv.y, o4.y, fmaf(xv.z, o4.z, xv.w * o4.w)));
            #pragma unroll
            for (int off = 32; off; off >>= 1) {
                aq += __shfl_down(aq, off, 64);
                ao += __shfl_down(ao, off, 64);
            }
            if (lane == 0) {
                qv[row] = aq + bq[row];
                ov[row] = 1.0f / (1.0f + __expf(-(ao + bo[row])));
            }
        }
    } else {                              // ---- transpose W[b][k] -> Wt[j][k][b]
        __shared__ float tl[32][33];
        int tb = bx - 519;
        int j = tb / 96, rem = tb % 96;
        int k0 = (rem / 12) * 32, b0 = (rem % 12) * 32;
        const float* W = (j == 0) ? Wk : (j == 1) ? Wi : Wf;
        int c = tid & 31, r0 = tid >> 5;
        #pragma unroll
        for (int s = 0; s < 4; ++s) {
            int r = r0 + 8 * s;
            tl[r][c] = W[(b0 + r) * 256 + k0 + c];
        }
        __syncthreads();
        float* dst = Wt + j * WTS;
        #pragma unroll
        for (int s = 0; s < 4; ++s) {
            int rr = r0 + 8 * s;
            dst[(k0 + rr) * 384 + b0 + c] = tl[c][rr];
        }
    }
}

// ========== K2: m4n4 SGEMM, tile 32t x 128b x 3 mats, grid (65,3) x 256 ==========
// tx=tid&31 -> 4 b's, ty=tid>>5 -> 4 t's. 48 acc/thread.
// Per kk per wave: 1 a-b128 (8-unique, broadcast) + 3 b-b128 vs 48 FMA -> near-balanced.
// Staging: b128 global loads from xpT/Wt, b128 LDS stores (no transpose), reg prefetch.
__global__ __launch_bounds__(256) void k2_proj(
    const float* __restrict__ xpT, const float* __restrict__ Wt,
    const float* __restrict__ bk, const float* __restrict__ bi, const float* __restrict__ bf,
    float* __restrict__ zk, float* __restrict__ ai, float* __restrict__ lf,
    float* __restrict__ cs) {
    __shared__ float alds[16][36];       // [k][t]
    __shared__ float wlds[3][16][132];   // [j][k][b]
    __shared__ float csred[8][132];
    int tid = threadIdx.x;
    int t0 = blockIdx.x * 32, b0 = blockIdx.y * 128;
    int tx = tid & 31, ty = tid >> 5;

    float acc[3][16];
    #pragma unroll
    for (int j = 0; j < 3; ++j)
        #pragma unroll
        for (int u = 0; u < 16; ++u) acc[j][u] = 0.0f;

    int ar = tid >> 3, ac = (tid & 7) * 4;    // A staging (tid<128)
    int wk = tid >> 4, wc = (tid & 15) * 8;   // W staging (all)

    float4 aR = {0.f, 0.f, 0.f, 0.f};
    float4 wR[3][2];
    if (tid < 128) aR = *(const float4*)&xpT[ar * TT + t0 + ac];
    #pragma unroll
    for (int j = 0; j < 3; ++j) {
        wR[j][0] = *(const float4*)&Wt[j * WTS + wk * 384 + b0 + wc];
        wR[j][1] = *(const float4*)&Wt[j * WTS + wk * 384 + b0 + wc + 4];
    }

    for (int kt = 0; kt < 16; ++kt) {
        __syncthreads();
        if (tid < 128) *(float4*)&alds[ar][ac] = aR;
        #pragma unroll
        for (int j = 0; j < 3; ++j) {
            *(float4*)&wlds[j][wk][wc] = wR[j][0];
            *(float4*)&wlds[j][wk][wc + 4] = wR[j][1];
        }
        __syncthreads();
        if (kt < 15) {
            int k0 = (kt + 1) * 16;
            if (tid < 128) aR = *(const float4*)&xpT[(k0 + ar) * TT + t0 + ac];
            #pragma unroll
            for (int j = 0; j < 3; ++j) {
                wR[j][0] = *(const float4*)&Wt[j * WTS + (k0 + wk) * 384 + b0 + wc];
                wR[j][1] = *(const float4*)&Wt[j * WTS + (k0 + wk) * 384 + b0 + wc + 4];
            }
        }
        #pragma unroll
        for (int kk = 0; kk < 16; ++kk) {
            float4 a4 = *(const float4*)&alds[kk][ty * 4];
            #pragma unroll
            for (int j = 0; j < 3; ++j) {
                float4 b4 = *(const float4*)&wlds[j][kk][tx * 4];
                acc[j][0]  = fmaf(a4.x, b4.x, acc[j][0]);
                acc[j][1]  = fmaf(a4.x, b4.y, acc[j][1]);
                acc[j][2]  = fmaf(a4.x, b4.z, acc[j][2]);
                acc[j][3]  = fmaf(a4.x, b4.w, acc[j][3]);
                acc[j][4]  = fmaf(a4.y, b4.x, acc[j][4]);
                acc[j][5]  = fmaf(a4.y, b4.y, acc[j][5]);
                acc[j][6]  = fmaf(a4.y, b4.z, acc[j][6]);
                acc[j][7]  = fmaf(a4.y, b4.w, acc[j][7]);
                acc[j][8]  = fmaf(a4.z, b4.x, acc[j][8]);
                acc[j][9]  = fmaf(a4.z, b4.y, acc[j][9]);
                acc[j][10] = fmaf(a4.z, b4.z, acc[j][10]);
                acc[j][11] = fmaf(a4.z, b4.w, acc[j][11]);
                acc[j][12] = fmaf(a4.w, b4.x, acc[j][12]);
                acc[j][13] = fmaf(a4.w, b4.y, acc[j][13]);
                acc[j][14] = fmaf(a4.w, b4.z, acc[j][14]);
                acc[j][15] = fmaf(a4.w, b4.w, acc[j][15]);
            }
        }
    }
    // ---- epilogue: bias + act, [t][b] b128 stores, 8-t chunk lf sums
    int col = b0 + tx * 4;
    float4 bk4 = *(const float4*)&bk[col];
    float4 bi4 = *(const float4*)&bi[col];
    float4 bf4 = *(const float4*)&bf[col];
    const float sc = 0.05103103630798287f;  // 1/sqrt(384)
    float4 ls = {0.f, 0.f, 0.f, 0.f};
    #pragma unroll
    for (int u = 0; u < 4; ++u) {
        int t = t0 + ty * 4 + u;
        if (t < TP) {
            int row = t * H + col;
            int o = u * 4;
            float4 v;
            v.x = (acc[0][o+0] + bk4.x) * sc; v.y = (acc[0][o+1] + bk4.y) * sc;
            v.z = (acc[0][o+2] + bk4.z) * sc; v.w = (acc[0][o+3] + bk4.w) * sc;
            *(float4*)&zk[row] = v;
            v.x = acc[1][o+0] + bi4.x; v.y = acc[1][o+1] + bi4.y;
            v.z = acc[1][o+2] + bi4.z; v.w = acc[1][o+3] + bi4.w;
            *(float4*)&ai[row] = v;
            float4 l;
            l.x = logsig(acc[2][o+0] + bf4.x); l.y = logsig(acc[2][o+1] + bf4.y);
            l.z = logsig(acc[2][o+2] + bf4.z); l.w = logsig(acc[2][o+3] + bf4.w);
            *(float4*)&lf[row] = l;
            ls.x += l.x; ls.y += l.y; ls.z += l.z; ls.w += l.w;
        }
    }
    *(float4*)&csred[ty][tx * 4] = ls;
    __syncthreads();
    // 4 chunks x 128 cols = 512 sums; combine ty-pairs
    #pragma unroll
    for (int r = 0; r < 2; ++r) {
        int idx = tid + 256 * r;
        int ch = idx >> 7, cc = idx & 127;
        float s = csred[ch * 2][cc] + csred[ch * 2 + 1][cc];
        cs[(blockIdx.x * 4 + ch) * H + b0 + cc] = s;
    }
}

// ========== TAIL: grid 257 x 384. cs-scan (8-acc pipelined) + chunk e + g + zp/Gc ==========
__global__ __launch_bounds__(384) void tail(
    const float* __restrict__ xp, const float* __restrict__ zk,
    const float* __restrict__ ai, const float* __restrict__ lf,
    const float* __restrict__ cs, const float* __restrict__ qv,
    float* __restrict__ zp, float* __restrict__ Gc) {
    __shared__ float gtl[6][8];
    __shared__ float gts[8];
    int tid = threadIdx.x;
    int w = tid >> 6, lane = tid & 63;
    int c = blockIdx.x, ts = c * 8;

    // suffix sum of cs rows c+1..259 — 8 independent accumulators (pipelined)
    float s0 = 0.f, s1 = 0.f, s2 = 0.f, s3 = 0.f, s4 = 0.f, s5 = 0.f, s6 = 0.f, s7 = 0.f;
    int cc = c + 1;
    for (; cc + 7 < NCS; cc += 8) {
        s0 += cs[(cc + 0) * H + tid];
        s1 += cs[(cc + 1) * H + tid];
        s2 += cs[(cc + 2) * H + tid];
        s3 += cs[(cc + 3) * H + tid];
        s4 += cs[(cc + 4) * H + tid];
        s5 += cs[(cc + 5) * H + tid];
        s6 += cs[(cc + 6) * H + tid];
        s7 += cs[(cc + 7) * H + tid];
    }
    for (; cc < NCS; ++cc) s0 += cs[cc * H + tid];
    float co0 = ((s0 + s1) + (s2 + s3)) + ((s4 + s5) + (s6 + s7));
    float qb = qv[tid];

    float aiv[8], lfv[8], zkv[8];
    #pragma unroll
    for (int u = 0; u < 8; ++u) {
        if (ts + u < TP) {
            int idx = (ts + u) * H + tid;
            aiv[u] = ai[idx]; lfv[u] = lf[idx]; zkv[u] = zk[idx];
        } else {
            aiv[u] = -1e30f; lfv[u] = 0.f; zkv[u] = 0.f;
        }
    }
    float S = 0.f;
    float e[8];
    #pragma unroll
    for (int u = 7; u >= 0; --u) {
        e[u] = __expf(aiv[u] + co0 + S) * zkv[u] * qb;
        S += lfv[u];
    }
    #pragma unroll
    for (int u = 0; u < 8; ++u) {
        float s = e[u];
        s += __shfl_xor(s, 1, 64);
        s += __shfl_xor(s, 2, 64);
        s += __shfl_xor(s, 4, 64);
        s += __shfl_xor(s, 8, 64);
        s += __shfl_xor(s, 16, 64);
        s += __shfl_xor(s, 32, 64);
        if (lane == 0) gtl[w][u] = s;
    }
    __syncthreads();
    if (tid < 8) {
        gts[tid] = gtl[0][tid] + gtl[1][tid] + gtl[2][tid]
                 + gtl[3][tid] + gtl[4][tid] + gtl[5][tid];
    }
    __syncthreads();
    if (tid < 256) {
        float z = 0.f;
        #pragma unroll
        for (int u = 0; u < 8; ++u)
            z = fmaf(gts[u], xp[(ts + u) * 256 + tid], z);   // gts=0 for t>=TP
        zp[c * 256 + tid] = z;
    }
    if (tid == 0)
        Gc[c] = ((gts[0] + gts[1]) + (gts[2] + gts[3])) + ((gts[4] + gts[5]) + (gts[6] + gts[7]));
}

// ========== FINAL: grid 96 x 256. Reduce zp/Gc (redundant per block) + GEMV ==========
__global__ __launch_bounds__(256) void kfinal(
    const float* __restrict__ zp, const float* __restrict__ Gc,
    const float* __restrict__ ov, const float* __restrict__ Wv,
    const float* __restrict__ bv, float* __restrict__ out) {
    __shared__ float zl[256];
    __shared__ float Gs;
    int tid = threadIdx.x;
    float t0 = 0.f, t1 = 0.f, t2 = 0.f, t3 = 0.f, t4 = 0.f, t5 = 0.f, t6 = 0.f, t7 = 0.f;
    int c = 0;
    for (; c + 7 < NC3; c += 8) {
        t0 += zp[(c + 0) * 256 + tid];
        t1 += zp[(c + 1) * 256 + tid];
        t2 += zp[(c + 2) * 256 + tid];
        t3 += zp[(c + 3) * 256 + tid];
        t4 += zp[(c + 4) * 256 + tid];
        t5 += zp[(c + 5) * 256 + tid];
        t6 += zp[(c + 6) * 256 + tid];
        t7 += zp[(c + 7) * 256 + tid];
    }
    for (; c < NC3; ++c) t0 += zp[c * 256 + tid];
    zl[tid] = ((t0 + t1) + (t2 + t3)) + ((t4 + t5) + (t6 + t7));
    if (tid < 64) {
        float g = 0.f;
        for (int cc = tid; cc < NC3; cc += 64) g += Gc[cc];
        #pragma unroll
        for (int off = 32; off; off >>= 1) g += __shfl_down(g, off, 64);
        if (tid == 0) Gs = g;
    }
    __syncthreads();
    float G = Gs;
    float den = fmaxf(fabsf(G), 1.0f);
    int wid = tid >> 6, lane = tid & 63;
    int row = blockIdx.x * 4 + wid;
    float4 wv4 = *(const float4*)&Wv[row * 256 + lane * 4];
    float4 z4 = *(const float4*)&zl[lane * 4];
    float a = fmaf(z4.x, wv4.x, fmaf(z4.y, wv4.y, fmaf(z4.z, wv4.z, z4.w * wv4.w)));
    #pragma unroll
    for (int off = 32; off; off >>= 1) a += __shfl_down(a, off, 64);
    if (lane == 0)
        out[row] = ov[row] * (a + bv[row] * G) / den;
}

extern "C" void kernel_launch(void* const* d_in, const int* in_sizes, int n_in,
                              void* d_out, int out_size, void* d_ws, size_t ws_size,
                              hipStream_t stream) {
    const float* x  = (const float*)d_in[0];
    const float* Wq = (const float*)d_in[1];  const float* bq = (const float*)d_in[2];
    const float* Wk = (const float*)d_in[3];  const float* bk = (const float*)d_in[4];
    const float* Wv = (const float*)d_in[5];  const float* bv = (const float*)d_in[6];
    const float* Wi = (const float*)d_in[7];  const float* bi = (const float*)d_in[8];
    const float* Wf = (const float*)d_in[9];  const float* bf = (const float*)d_in[10];
    const float* Wo = (const float*)d_in[11]; const float* bo = (const float*)d_in[12];
    const float* cw = (const float*)d_in[13]; const float* cb = (const float*)d_in[14];
    float* out = (float*)d_out;

    float* ws = (float*)d_ws;
    float* xp  = ws;                       // TP*F   = 525056
    float* xpT = xp  + TP * F;             // 256*2080 = 532480
    float* Wt  = xpT + 256 * TT;           // 3*98304 = 294912
    float* zk  = Wt  + 3 * WTS;            // TP*H = 787584
    float* ai  = zk  + TP * H;             // TP*H
    float* lf  = ai  + TP * H;             // TP*H
    float* cs  = lf  + TP * H;             // NCS*H = 99840
    float* qv  = cs  + NCS * H;            // H
    float* ov  = qv  + H;                  // H
    float* zp  = ov  + H;                  // NC3*256 = 65792
    float* Gc  = zp  + NC3 * 256;          // NC3 (+pad)

    prep<<<807, 256, 0, stream>>>(x, cw, cb, Wk, Wi, Wf, Wq, bq, Wo, bo,
                                  xp, xpT, Wt, qv, ov);
    k2_proj<<<dim3(65, 3), 256, 0, stream>>>(xpT, Wt, bk, bi, bf, zk, ai, lf, cs);
    tail<<<NC3, 384, 0, stream>>>(xp, zk, ai, lf, cs, qv, zp, Gc);
    kfinal<<<96, 256, 0, stream>>>(zp, Gc, ov, Wv, bv, out);
}